// Round 15
// baseline (1478.740 us; speedup 1.0000x reference)
//
#include <hip/hip_runtime.h>

typedef unsigned short u16;
typedef __attribute__((ext_vector_type(4))) float f32x4;
typedef __attribute__((ext_vector_type(8))) __bf16 bf16x8;   // MFMA operands
typedef __attribute__((ext_vector_type(8))) short s16x8;     // generic 16B data
typedef __attribute__((ext_vector_type(4))) u16 u16x4;

#define N_NODES 20000
#define N_EDGES 160000
#define N_GRAPH 32
#define F_IN 67
#define HID 2048
#define PW 1024
#define NCLS 18
#define MPAD2 20224   // 79 * 256  (256-tile gemm grid, buffer row count)
#define K1 192        // padded concat-K for layer 1 (67 + 67 -> 192)

__device__ __forceinline__ float bf2f(u16 u) {
    unsigned v = ((unsigned)u) << 16;
    float f; __builtin_memcpy(&f, &v, 4); return f;
}
__device__ __forceinline__ u16 f2bf(float f) {
    unsigned u; __builtin_memcpy(&u, &f, 4);
    u = (u + 0x7FFF + ((u >> 16) & 1)) >> 16;
    return (u16)u;
}
__device__ __forceinline__ int imax(int a, int b) { return a > b ? a : b; }

// ---- async global->LDS, 16B per lane ----
__device__ __forceinline__ void ld16(const u16* gptr, u16* lptr) {
    __builtin_amdgcn_global_load_lds(
        (const __attribute__((address_space(1))) unsigned int*)gptr,
        (__attribute__((address_space(3))) unsigned int*)lptr,
        16, 0, 0);
}

// =================== CSR build ===================
__global__ void k_hist(const int* __restrict__ dst, int* __restrict__ cnt) {
    int e = blockIdx.x * 256 + threadIdx.x;
    if (e < N_EDGES) atomicAdd(&cnt[dst[e]], 1);
}

__global__ void k_scan(const int* __restrict__ cnt, int* __restrict__ rowptr) {
    __shared__ int part[256];
    int t = threadIdx.x;
    const int per = (N_NODES + 255) / 256;   // 79
    int base = t * per;
    int s = 0;
    for (int i = 0; i < per; i++) { int idx = base + i; if (idx < N_NODES) s += cnt[idx]; }
    part[t] = s; __syncthreads();
    for (int off = 1; off < 256; off <<= 1) {
        int v = (t >= off) ? part[t - off] : 0;
        __syncthreads();
        part[t] += v;
        __syncthreads();
    }
    int running = (t == 0) ? 0 : part[t - 1];
    for (int i = 0; i < per; i++) {
        int idx = base + i;
        if (idx < N_NODES) { rowptr[idx] = running; running += cnt[idx]; }
    }
    if (t == 255) rowptr[N_NODES] = running;
}

__global__ void k_scatter(const int* __restrict__ src, const int* __restrict__ dst,
                          const int* __restrict__ rowptr, int* __restrict__ cursor,
                          int* __restrict__ csr) {
    int e = blockIdx.x * 256 + threadIdx.x;
    if (e < N_EDGES) {
        int d = dst[e];
        int p = atomicAdd(&cursor[d], 1);
        csr[rowptr[d] + p] = src[e];
    }
}

// =================== weight prep ===================
__global__ void k_w1t(const float* __restrict__ ws1, const float* __restrict__ wn1,
                      u16* __restrict__ w1t) {
    int n = blockIdx.x, t = threadIdx.x;   // 192 threads
    float v = 0.f;
    if (t < F_IN) v = ws1[(size_t)t * HID + n];
    else if (t < 2 * F_IN) v = wn1[(size_t)(t - F_IN) * HID + n];
    w1t[(size_t)n * K1 + t] = f2bf(v);
}

// transpose-convert BOTH f32 [HID][HID] weights -> bf16 dst[n][2*HID]
__global__ void k_transpose2(const float* __restrict__ s0, const float* __restrict__ s1,
                             u16* __restrict__ dst) {
    __shared__ float tile[32][33];
    const float* src = blockIdx.z ? s1 : s0;
    int colofs = blockIdx.z ? HID : 0;
    int bx = blockIdx.x * 32, by = blockIdx.y * 32;
    int tx = threadIdx.x, ty = threadIdx.y;   // (32,8)
#pragma unroll
    for (int i = 0; i < 32; i += 8)
        tile[ty + i][tx] = src[(size_t)(by + ty + i) * HID + bx + tx];
    __syncthreads();
#pragma unroll
    for (int i = 0; i < 32; i += 8)
        dst[(size_t)(bx + ty + i) * (2 * HID) + colofs + by + tx] = f2bf(tile[tx][ty + i]);
}

// =================== layer 1 input build ===================
__global__ void k_agg1(const float* __restrict__ h, const int* __restrict__ rowptr,
                       const int* __restrict__ csr, u16* __restrict__ acat) {
    int n = blockIdx.x, t = threadIdx.x;   // 192 threads
    if (t < F_IN) {
        acat[(size_t)n * K1 + t] = f2bf(h[(size_t)n * F_IN + t]);
    } else if (t < 2 * F_IN) {
        int c = t - F_IN;
        int e0 = rowptr[n], e1 = rowptr[n + 1];
        float a = 0.f;
        for (int e = e0; e < e1; e++) a += h[(size_t)csr[e] * F_IN + c];
        acat[(size_t)n * K1 + F_IN + c] = f2bf(a / (float)imax(e1 - e0, 1));
    }
}

// =================== fused BN+leaky + self-write + neighbor-mean ===================
__global__ __launch_bounds__(256)
void k_aggbn(const u16* __restrict__ x,
             const float* __restrict__ ssum, const float* __restrict__ ssq,
             const float* __restrict__ gma, const float* __restrict__ bta,
             const int* __restrict__ rowptr, const int* __restrict__ csr,
             u16* __restrict__ self_out, u16* __restrict__ neigh_out) {
    int n = blockIdx.x, t = threadIdx.x;
    int col = t * 8;
    float a[8], d[8];
#pragma unroll
    for (int j = 0; j < 8; ++j) {
        float m = ssum[col + j] * (1.0f / N_NODES);
        float var = ssq[col + j] * (1.0f / N_NODES) - m * m;
        a[j] = gma[col + j] * rsqrtf(var + 1e-5f);
        d[j] = bta[col + j] - m * a[j];
    }
    s16x8 vs = *(const s16x8*)&x[(size_t)n * HID + col];
    s16x8 so;
#pragma unroll
    for (int j = 0; j < 8; ++j) {
        float f = bf2f((u16)vs[j]) * a[j] + d[j];
        f = fmaxf(f, 0.01f * f);
        so[j] = (short)f2bf(f);
    }
    *(s16x8*)&self_out[(size_t)n * HID + col] = so;
    int e0 = rowptr[n], e1 = rowptr[n + 1];
    float acc[8] = {0, 0, 0, 0, 0, 0, 0, 0};
    for (int e = e0; e < e1; ++e) {
        int s = csr[e];
        s16x8 v = *(const s16x8*)&x[(size_t)s * HID + col];
#pragma unroll
        for (int j = 0; j < 8; ++j) {
            float f = bf2f((u16)v[j]) * a[j] + d[j];
            acc[j] += fmaxf(f, 0.01f * f);
        }
    }
    float inv = 1.0f / (float)imax(e1 - e0, 1);
    s16x8 o;
#pragma unroll
    for (int j = 0; j < 8; ++j) o[j] = (short)f2bf(acc[j] * inv);
    *(s16x8*)&neigh_out[(size_t)n * HID + col] = o;
}

// =================== unified GEMM: 256x256, BK=32, 2 blocks/CU ===================
// Round-15: LDS halved (64 KiB: LA/LB = 2 bufs x [128 phys rows][64 u16], two
// 32-elem logical rows packed per 128B phys row) -> 2 blocks/CU for implicit
// cross-block stall filling (m114). Swizzle: phys byte = logical ^ ((q&7)<<4)
// within each 128B row (2-way bank aliasing = free). Staging linear-dest +
// inverse-swizzled global source; 4 ld16/thread/tile; ONE vmcnt(2) per tile
// (drains all 4 loads of current tile, leaves next A in flight).
// 4 phases x 8 MFMA, quadrant order (0,0),(0,1),(1,1),(1,0), bw carried p0->p3.
#define VM2 asm volatile("s_waitcnt vmcnt(2)" ::: "memory")
#define VM0 asm volatile("s_waitcnt vmcnt(0)" ::: "memory")
#define BAR __builtin_amdgcn_s_barrier();

#define STAGE_A() { const u16* as_; int ktl_;                                       \
    if (kt1 < kskt) { as_ = A0; ktl_ = kt1; } else { as_ = A1; ktl_ = kt1 - kskt; } \
    size_t kb_ = (size_t)ktl_ * 32 + ksl;                                           \
    ld16(as_ + (row0 + grow0) * (size_t)lda + kb_, LA + dbo + ldsoff);              \
    ld16(as_ + (row0 + grow0 + 128) * (size_t)lda + kb_, LA + dbo + 4096 + ldsoff); }

#define STAGE_B() { size_t kb_ = (size_t)kt1 * 32 + ksl;                            \
    ld16(WT + (size_t)(col0 + grow0) * ldb + kb_, LB + dbo + ldsoff);               \
    ld16(WT + (size_t)(col0 + grow0 + 128) * ldb + kb_, LB + dbo + 4096 + ldsoff); }

#define RD_A(QM) { _Pragma("unroll") for (int f = 0; f < 4; ++f)                    \
    af[f] = *(const bf16x8*)(bA + ((QM) * 64 + aq + f * 8) * 128 + hbx); }

#define RD_B(DST, QN) { _Pragma("unroll") for (int n = 0; n < 2; ++n)               \
    DST[n] = *(const bf16x8*)(bB + ((QN) * 64 + bq + n * 8) * 128 + hbx); }

#define MM8(QM, QN, BW) {                                                           \
    __builtin_amdgcn_s_setprio(1);                                                  \
    _Pragma("unroll") for (int f = 0; f < 4; ++f)                                   \
      _Pragma("unroll") for (int n = 0; n < 2; ++n)                                 \
        acc[(QM) * 4 + f][(QN) * 2 + n] = __builtin_amdgcn_mfma_f32_16x16x32_bf16(  \
            BW[n], af[f], acc[(QM) * 4 + f][(QN) * 2 + n], 0, 0, 0);                \
    __builtin_amdgcn_s_setprio(0); }

__global__ __launch_bounds__(512)
void k_gemm256(const u16* __restrict__ A0, const u16* __restrict__ A1,
               const u16* __restrict__ WT, u16* __restrict__ C,
               float* __restrict__ ssum, float* __restrict__ ssq,
               int nkt, int kskt, int lda, int ldb) {
    __shared__ u16 LA[2 * 128 * 64];   // 32 KB
    __shared__ u16 LB[2 * 128 * 64];   // 32 KB
    const int tid = threadIdx.x;
    const int lane = tid & 63;
    const int wave = tid >> 6;
    const int wm = wave >> 2, wn = wave & 3;   // 2 x 4 waves -> 128x64 C each
    const int lr = lane & 15, lg = lane >> 4;

    // row-slab XCD mapping (bijective: 632 = 79 rows x 8 cols)
    const int g = (blockIdx.x & 7) * 79 + (blockIdx.x >> 3);
    const size_t row0 = (size_t)(g >> 3) * 256;
    const int col0 = (g & 7) * 256;

    // staging precompute (512 thr x 16B = 8 KB/issue = 64 phys rows; 2 issues/op)
    const int q0 = tid >> 3;                          // phys row in issue 0
    const int lg16 = ((tid & 7) * 16) ^ ((q0 & 7) << 4);  // logical offset in 128B row
    const int grow0 = 2 * q0 + (lg16 >> 6);           // logical global row (issue 0)
    const int ksl = ((lg16 >> 4) & 3) * 8;            // u16 k-offset within 32-row
    const int ldsoff = tid * 8;                       // u16 linear dest (issue 0)

    // read-side precompute
    const int aq = wm * 32 + (lr >> 1);
    const int bq = wn * 16 + (lr >> 1);
    const int hbx = (((lane & 1) * 64 + lg * 16) ^ (((lr >> 1) & 7) << 4));

    f32x4 acc[8][4];
#pragma unroll
    for (int i = 0; i < 8; i++)
#pragma unroll
        for (int j = 0; j < 4; j++) acc[i][j] = f32x4{0.f, 0.f, 0.f, 0.f};

    // prologue: tile 0 -> buf 0
    {
        const int kt1 = 0; const int dbo = 0;
        STAGE_A() STAGE_B()
    }
    VM0;
    BAR

    bf16x8 af[4], bw[2], bw2[2];

    for (int t = 0; t < nkt - 1; ++t) {
        const char* bA = (const char*)LA + (t & 1) * 16384;
        const char* bB = (const char*)LB + (t & 1) * 16384;
        const int kt1 = t + 1;
        const int dbo = ((t + 1) & 1) * 8192;
        // p0: read A-q0 + B-q0; stage next A; single counted wait of the tile
        RD_A(0) RD_B(bw, 0) STAGE_A() VM2; BAR MM8(0, 0, bw)
        // p1: read B-q1 (keep af); stage next B
        RD_B(bw2, 1) STAGE_B() BAR MM8(0, 1, bw2)
        // p2: read A-q1 (keep bw2)
        RD_A(1) BAR MM8(1, 1, bw2)
        // p3: register-only (af=A1, bw carried from p0); no barrier
        MM8(1, 0, bw)
    }
    {   // tail tile nkt-1 (no staging): full drain at p0
        const char* bA = (const char*)LA + ((nkt - 1) & 1) * 16384;
        const char* bB = (const char*)LB + ((nkt - 1) & 1) * 16384;
        RD_A(0) RD_B(bw, 0) VM0; BAR MM8(0, 0, bw)
        RD_B(bw2, 1) BAR MM8(0, 1, bw2)
        RD_A(1) BAR MM8(1, 1, bw2)
        MM8(1, 0, bw)
    }

    // epilogue: C write; acc[i][j]: i = QM*4+f -> m, j = QN*2+n -> col block
#pragma unroll
    for (int i = 0; i < 8; ++i) {
        size_t m = row0 + (i >> 2) * 128 + wm * 64 + (i & 3) * 16 + lr;
#pragma unroll
        for (int j = 0; j < 4; ++j) {
            int cb = col0 + (j >> 1) * 128 + wn * 32 + (j & 1) * 16 + lg * 4;
            u16x4 o;
#pragma unroll
            for (int rg = 0; rg < 4; ++rg) o[rg] = f2bf(acc[i][j][rg]);
            *(u16x4*)&C[m * HID + cb] = o;
        }
    }
    // fused BN column-stats: sum over i in-lane, reduce over lr (lanes 0-15 of
    // each lg group share the same 4 columns), one atomicAdd pair per (j,rg).
#pragma unroll
    for (int j = 0; j < 4; ++j) {
#pragma unroll
        for (int rg = 0; rg < 4; ++rg) {
            float s = 0.f, s2 = 0.f;
#pragma unroll
            for (int i = 0; i < 8; ++i) { float v = acc[i][j][rg]; s += v; s2 += v * v; }
#pragma unroll
            for (int mk = 1; mk < 16; mk <<= 1) {
                s += __shfl_xor(s, mk, 64);
                s2 += __shfl_xor(s2, mk, 64);
            }
            if (lr == 0) {
                int cb = col0 + (j >> 1) * 128 + wn * 32 + (j & 1) * 16 + lg * 4 + rg;
                atomicAdd(&ssum[cb], s);
                atomicAdd(&ssq[cb], s2);
            }
        }
    }
}

// =================== pooling (BN+leaky fused) + MLP ===================
__global__ void k_bounds(const int* __restrict__ gids, int* __restrict__ gstart) {
    int t = threadIdx.x;
    if (t > N_GRAPH) return;
    int lo = 0, hi = N_NODES;
    while (lo < hi) { int mid = (lo + hi) >> 1; if (gids[mid] < t) lo = mid + 1; else hi = mid; }
    gstart[t] = lo;
}

__global__ void k_poolbn(const u16* __restrict__ x,
                         const float* __restrict__ ssum, const float* __restrict__ ssq,
                         const float* __restrict__ gma, const float* __restrict__ bta,
                         const int* __restrict__ gstart, float* __restrict__ hg) {
    int g = blockIdx.x;
    int col = blockIdx.y * 256 + threadIdx.x;
    float m = ssum[col] * (1.0f / N_NODES);
    float var = ssq[col] * (1.0f / N_NODES) - m * m;
    float a = gma[col] * rsqrtf(var + 1e-5f);
    float d = bta[col] - m * a;
    int r0 = gstart[g], r1 = gstart[g + 1];
    float s = 0.f;
    for (int r = r0; r < r1; r++) {
        float f = bf2f(x[(size_t)r * HID + col]) * a + d;
        s += fmaxf(f, 0.01f * f);
    }
    hg[(size_t)g * HID + col] = s / (float)imax(r1 - r0, 1);
}

// k-split partial GEMM: Yp[kc][32][Nc] = X[32][kc-chunk] @ W[chunk][Nc]
__global__ __launch_bounds__(256)
void k_mlp_part(const float* __restrict__ X, const float* __restrict__ W,
                float* __restrict__ Yp, int K, int Nc) {
    __shared__ float xs[32 * 256];
    int t = threadIdx.x;
    int kc = blockIdx.y;
    int n = blockIdx.x * 64 + (t & 63);
    int mg = t >> 6;
#pragma unroll
    for (int l = 0; l < 32; ++l) {
        int e = l * 256 + t;
        xs[e] = X[(size_t)(e >> 8) * K + kc * 256 + (e & 255)];
    }
    __syncthreads();
    float acc[8] = {};
    for (int k = 0; k < 256; ++k) {
        float wv = W[(size_t)(kc * 256 + k) * Nc + n];
#pragma unroll
        for (int i = 0; i < 8; ++i) acc[i] += xs[(mg * 8 + i) * 256 + k] * wv;
    }
#pragma unroll
    for (int i = 0; i < 8; ++i)
        Yp[(size_t)(kc * 32 + mg * 8 + i) * Nc + n] = acc[i];
}

// deterministic reduce over 8 k-chunks + bias + leaky
__global__ void k_mlp_red(const float* __restrict__ Yp, const float* __restrict__ bias,
                          float* __restrict__ Y, int Nc, int leaky) {
    int idx = blockIdx.x * 256 + threadIdx.x;   // m*Nc + n
    int n = idx % Nc;
    float s = 0.f;
#pragma unroll
    for (int kc = 0; kc < 8; ++kc) s += Yp[(size_t)kc * 32 * Nc + idx];
    float v = s + bias[n];
    if (leaky) v = v > 0.f ? v : 0.01f * v;
    Y[idx] = v;
}

__global__ void k_fc3(const float* __restrict__ y2, const float* __restrict__ fw3,
                      const float* __restrict__ fb3, float* __restrict__ out) {
    __shared__ float red[8][32];
    int m = blockIdx.x, t = threadIdx.x;
    int ch = t >> 5, c = t & 31;
    float s = 0.f;
    if (c < NCLS) {
        for (int j = 0; j < 128; ++j) {
            int k = ch * 128 + j;
            s += y2[(size_t)m * PW + k] * fw3[(size_t)k * NCLS + c];
        }
    }
    red[ch][c] = s;
    __syncthreads();
    if (t < NCLS) {
        float a = 0.f;
#pragma unroll
        for (int c2 = 0; c2 < 8; ++c2) a += red[c2][t];
        out[m * NCLS + t] = a + fb3[t];
    }
}

// =================== launcher ===================
extern "C" void kernel_launch(void* const* d_in, const int* in_sizes, int n_in,
                              void* d_out, int out_size, void* d_ws, size_t ws_size,
                              hipStream_t stream) {
    const float* h   = (const float*)d_in[0];
    const int* src   = (const int*)d_in[1];
    const int* dst   = (const int*)d_in[2];
    const int* gids  = (const int*)d_in[3];
    const float* ws1 = (const float*)d_in[4];
    const float* wn1 = (const float*)d_in[5];
    const float* ws2 = (const float*)d_in[7];
    const float* wn2 = (const float*)d_in[8];
    const float* ws3 = (const float*)d_in[10];
    const float* wn3 = (const float*)d_in[11];
    const float* g1  = (const float*)d_in[13];
    const float* be1 = (const float*)d_in[14];
    const float* g2  = (const float*)d_in[15];
    const float* be2 = (const float*)d_in[16];
    const float* g3  = (const float*)d_in[17];
    const float* be3 = (const float*)d_in[18];
    const float* fw1 = (const float*)d_in[19];
    const float* fb1 = (const float*)d_in[20];
    const float* fw2 = (const float*)d_in[21];
    const float* fb2 = (const float*)d_in[22];
    const float* fw3 = (const float*)d_in[23];
    const float* fb3 = (const float*)d_in[24];
    float* out = (float*)d_out;
    (void)in_sizes; (void)n_in; (void)out_size;

    char* base = (char*)d_ws;
    size_t off = 0;
    auto alloc = [&](size_t b) -> char* {
        char* p = base + off;
        off += (b + 255) & ~(size_t)255;
        return p;
    };
    u16* BUF0 = (u16*)alloc((size_t)MPAD2 * HID * 2);
    u16* BUF1 = (u16*)alloc((size_t)MPAD2 * HID * 2);
    u16* BUF2 = (u16*)alloc((size_t)MPAD2 * HID * 2);
    u16* WT   = (u16*)alloc((size_t)HID * 2 * HID * 2);   // reused for layer 2 then 3
    int* cnt    = (int*)alloc(N_NODES * 4);
    int* rowptr = (int*)alloc((N_NODES + 1) * 4);
    int* cursor = (int*)alloc(N_NODES * 4);
    int* csr    = (int*)alloc(N_EDGES * 4);
    float* ssum = (float*)alloc(HID * 4);
    float* ssq  = (float*)alloc(HID * 4);
    int* gstart = (int*)alloc(64 * 4);
    float* hg = (float*)alloc((size_t)N_GRAPH * HID * 4);
    float* y1 = (float*)alloc((size_t)N_GRAPH * HID * 4);
    float* y2 = (float*)alloc((size_t)N_GRAPH * PW * 4);
    // aliases into BUF2 (free at the time of use)
    u16* ACAT = (u16*)((char*)BUF2);                            // layer-1 input [MPAD2][K1]
    u16* W1T  = (u16*)((char*)BUF2 + (size_t)MPAD2 * K1 * 2);   // layer-1 weights [HID][K1]
    float* Yp = (float*)((char*)BUF2);                           // MLP partials (after L3)

    if (off > ws_size) return;   // diagnostic guard

    hipMemsetAsync(cnt, 0, N_NODES * 4, stream);
    hipMemsetAsync(cursor, 0, N_NODES * 4, stream);
    hipMemsetAsync(ACAT, 0, (size_t)MPAD2 * K1 * 2, stream);
    // zero pad rows (20000..20223) of BUF1/BUF2 so gemm A-pads are exact zeros
    hipMemsetAsync(BUF1 + (size_t)N_NODES * HID, 0, (size_t)(MPAD2 - N_NODES) * HID * 2, stream);
    hipMemsetAsync(BUF2 + (size_t)N_NODES * HID, 0, (size_t)(MPAD2 - N_NODES) * HID * 2, stream);

    k_hist<<<(N_EDGES + 255) / 256, 256, 0, stream>>>(dst, cnt);
    k_scan<<<1, 256, 0, stream>>>(cnt, rowptr);
    k_scatter<<<(N_EDGES + 255) / 256, 256, 0, stream>>>(src, dst, rowptr, cursor, csr);

    k_w1t<<<HID, K1, 0, stream>>>(ws1, wn1, W1T);
    k_agg1<<<N_NODES, 192, 0, stream>>>(h, rowptr, csr, ACAT);

    dim3 tb(32, 8);
    // ---- layer 1 (K=192: 6 K-tiles of 32; stats fused into gemm) ----
    hipMemsetAsync(ssum, 0, 2 * HID * 4, stream);
    k_gemm256<<<632, 512, 0, stream>>>(ACAT, ACAT, W1T, BUF0, ssum, ssq, 6, 6, K1, K1);
    k_aggbn<<<N_NODES, 256, 0, stream>>>(BUF0, ssum, ssq, g1, be1, rowptr, csr, BUF1, BUF2);
    // ---- layer 2 ----
    k_transpose2<<<dim3(64, 64, 2), tb, 0, stream>>>(ws2, wn2, WT);
    hipMemsetAsync(ssum, 0, 2 * HID * 4, stream);
    k_gemm256<<<632, 512, 0, stream>>>(BUF1, BUF2, WT, BUF0, ssum, ssq, 128, 64, HID, 2 * HID);
    k_aggbn<<<N_NODES, 256, 0, stream>>>(BUF0, ssum, ssq, g2, be2, rowptr, csr, BUF1, BUF2);
    // ---- layer 3 ----
    k_transpose2<<<dim3(64, 64, 2), tb, 0, stream>>>(ws3, wn3, WT);
    hipMemsetAsync(ssum, 0, 2 * HID * 4, stream);
    k_gemm256<<<632, 512, 0, stream>>>(BUF1, BUF2, WT, BUF0, ssum, ssq, 128, 64, HID, 2 * HID);
    // ---- pooling (BN+leaky fused) + MLP head ----
    k_bounds<<<1, 64, 0, stream>>>(gids, gstart);
    k_poolbn<<<dim3(N_GRAPH, HID / 256), 256, 0, stream>>>(BUF0, ssum, ssq, g3, be3, gstart, hg);
    k_mlp_part<<<dim3(HID / 64, 8), 256, 0, stream>>>(hg, fw1, Yp, HID, HID);
    k_mlp_red<<<(N_GRAPH * HID) / 256, 256, 0, stream>>>(Yp, fb1, y1, HID, 1);
    k_mlp_part<<<dim3(PW / 64, 8), 256, 0, stream>>>(y1, fw2, Yp, HID, PW);
    k_mlp_red<<<(N_GRAPH * PW) / 256, 256, 0, stream>>>(Yp, fb2, y2, PW, 1);
    k_fc3<<<N_GRAPH, 256, 0, stream>>>(y2, fw3, fb3, out);
}

// Round 16
// 1347.789 us; speedup vs baseline: 1.0972x; 1.0972x over previous
//
#include <hip/hip_runtime.h>

typedef unsigned short u16;
typedef __attribute__((ext_vector_type(4))) float f32x4;
typedef __attribute__((ext_vector_type(8))) __bf16 bf16x8;   // MFMA operands
typedef __attribute__((ext_vector_type(8))) short s16x8;     // generic 16B data
typedef __attribute__((ext_vector_type(4))) u16 u16x4;

#define N_NODES 20000
#define N_EDGES 160000
#define N_GRAPH 32
#define F_IN 67
#define HID 2048
#define PW 1024
#define NCLS 18
#define MPAD2 20224   // 79 * 256  (256-tile gemm grid, buffer row count)
#define K1 192        // padded concat-K for layer 1 (67 + 67 -> 192)

__device__ __forceinline__ float bf2f(u16 u) {
    unsigned v = ((unsigned)u) << 16;
    float f; __builtin_memcpy(&f, &v, 4); return f;
}
__device__ __forceinline__ u16 f2bf(float f) {
    unsigned u; __builtin_memcpy(&u, &f, 4);
    u = (u + 0x7FFF + ((u >> 16) & 1)) >> 16;
    return (u16)u;
}
__device__ __forceinline__ int imax(int a, int b) { return a > b ? a : b; }

// ---- async global->LDS, 16B per lane ----
__device__ __forceinline__ void ld16(const u16* gptr, u16* lptr) {
    __builtin_amdgcn_global_load_lds(
        (const __attribute__((address_space(1))) unsigned int*)gptr,
        (__attribute__((address_space(3))) unsigned int*)lptr,
        16, 0, 0);
}

// =================== CSR build ===================
__global__ void k_hist(const int* __restrict__ dst, int* __restrict__ cnt) {
    int e = blockIdx.x * 256 + threadIdx.x;
    if (e < N_EDGES) atomicAdd(&cnt[dst[e]], 1);
}

__global__ void k_scan(const int* __restrict__ cnt, int* __restrict__ rowptr) {
    __shared__ int part[256];
    int t = threadIdx.x;
    const int per = (N_NODES + 255) / 256;   // 79
    int base = t * per;
    int s = 0;
    for (int i = 0; i < per; i++) { int idx = base + i; if (idx < N_NODES) s += cnt[idx]; }
    part[t] = s; __syncthreads();
    for (int off = 1; off < 256; off <<= 1) {
        int v = (t >= off) ? part[t - off] : 0;
        __syncthreads();
        part[t] += v;
        __syncthreads();
    }
    int running = (t == 0) ? 0 : part[t - 1];
    for (int i = 0; i < per; i++) {
        int idx = base + i;
        if (idx < N_NODES) { rowptr[idx] = running; running += cnt[idx]; }
    }
    if (t == 255) rowptr[N_NODES] = running;
}

__global__ void k_scatter(const int* __restrict__ src, const int* __restrict__ dst,
                          const int* __restrict__ rowptr, int* __restrict__ cursor,
                          int* __restrict__ csr) {
    int e = blockIdx.x * 256 + threadIdx.x;
    if (e < N_EDGES) {
        int d = dst[e];
        int p = atomicAdd(&cursor[d], 1);
        csr[rowptr[d] + p] = src[e];
    }
}

// =================== weight prep ===================
__global__ void k_w1t(const float* __restrict__ ws1, const float* __restrict__ wn1,
                      u16* __restrict__ w1t) {
    int n = blockIdx.x, t = threadIdx.x;   // 192 threads
    float v = 0.f;
    if (t < F_IN) v = ws1[(size_t)t * HID + n];
    else if (t < 2 * F_IN) v = wn1[(size_t)(t - F_IN) * HID + n];
    w1t[(size_t)n * K1 + t] = f2bf(v);
}

// transpose-convert BOTH f32 [HID][HID] weights -> bf16 dst[n][2*HID]
__global__ void k_transpose2(const float* __restrict__ s0, const float* __restrict__ s1,
                             u16* __restrict__ dst) {
    __shared__ float tile[32][33];
    const float* src = blockIdx.z ? s1 : s0;
    int colofs = blockIdx.z ? HID : 0;
    int bx = blockIdx.x * 32, by = blockIdx.y * 32;
    int tx = threadIdx.x, ty = threadIdx.y;   // (32,8)
#pragma unroll
    for (int i = 0; i < 32; i += 8)
        tile[ty + i][tx] = src[(size_t)(by + ty + i) * HID + bx + tx];
    __syncthreads();
#pragma unroll
    for (int i = 0; i < 32; i += 8)
        dst[(size_t)(bx + ty + i) * (2 * HID) + colofs + by + tx] = f2bf(tile[tx][ty + i]);
}

// =================== layer 1 input build ===================
__global__ void k_agg1(const float* __restrict__ h, const int* __restrict__ rowptr,
                       const int* __restrict__ csr, u16* __restrict__ acat) {
    int n = blockIdx.x, t = threadIdx.x;   // 192 threads
    if (t < F_IN) {
        acat[(size_t)n * K1 + t] = f2bf(h[(size_t)n * F_IN + t]);
    } else if (t < 2 * F_IN) {
        int c = t - F_IN;
        int e0 = rowptr[n], e1 = rowptr[n + 1];
        float a = 0.f;
        for (int e = e0; e < e1; e++) a += h[(size_t)csr[e] * F_IN + c];
        acat[(size_t)n * K1 + F_IN + c] = f2bf(a / (float)imax(e1 - e0, 1));
    }
}

// =================== fused BN+leaky + self-write + neighbor-mean ===================
// Reads raw GEMM output x (BUF0) + column stats; per-thread a[8],d[8] computed once.
// Writes normalized self row -> self_out (BUF1) and activated neighbor mean ->
// neigh_out (BUF2). Replaces the separate bnleaky pass (saves 164 MB/layer).
__global__ __launch_bounds__(256)
void k_aggbn(const u16* __restrict__ x,
             const float* __restrict__ ssum, const float* __restrict__ ssq,
             const float* __restrict__ gma, const float* __restrict__ bta,
             const int* __restrict__ rowptr, const int* __restrict__ csr,
             u16* __restrict__ self_out, u16* __restrict__ neigh_out) {
    int n = blockIdx.x, t = threadIdx.x;
    int col = t * 8;
    float a[8], d[8];
#pragma unroll
    for (int j = 0; j < 8; ++j) {
        float m = ssum[col + j] * (1.0f / N_NODES);
        float var = ssq[col + j] * (1.0f / N_NODES) - m * m;
        a[j] = gma[col + j] * rsqrtf(var + 1e-5f);
        d[j] = bta[col + j] - m * a[j];
    }
    // self row: bn + leaky -> BUF1
    s16x8 vs = *(const s16x8*)&x[(size_t)n * HID + col];
    s16x8 so;
#pragma unroll
    for (int j = 0; j < 8; ++j) {
        float f = bf2f((u16)vs[j]) * a[j] + d[j];
        f = fmaxf(f, 0.01f * f);
        so[j] = (short)f2bf(f);
    }
    *(s16x8*)&self_out[(size_t)n * HID + col] = so;
    // neighbors: mean of activated rows -> BUF2
    int e0 = rowptr[n], e1 = rowptr[n + 1];
    float acc[8] = {0, 0, 0, 0, 0, 0, 0, 0};
    for (int e = e0; e < e1; ++e) {
        int s = csr[e];
        s16x8 v = *(const s16x8*)&x[(size_t)s * HID + col];
#pragma unroll
        for (int j = 0; j < 8; ++j) {
            float f = bf2f((u16)v[j]) * a[j] + d[j];
            acc[j] += fmaxf(f, 0.01f * f);
        }
    }
    float inv = 1.0f / (float)imax(e1 - e0, 1);
    s16x8 o;
#pragma unroll
    for (int j = 0; j < 8; ++j) o[j] = (short)f2bf(acc[j] * inv);
    *(s16x8*)&neigh_out[(size_t)n * HID + col] = o;
}

// =================== unified GEMM: 256x256 (round-12/14 verified best) ===================
#define VM4 asm volatile("s_waitcnt vmcnt(4)" ::: "memory")
#define VM2 asm volatile("s_waitcnt vmcnt(2)" ::: "memory")
#define VM0 asm volatile("s_waitcnt vmcnt(0)" ::: "memory")

#define STAGE_A(H) { const u16* as_; int ktl_;                                      \
    if (kt1 < kskt) { as_ = A0; ktl_ = kt1; } else { as_ = A1; ktl_ = kt1 - kskt; } \
    size_t ko_ = (size_t)ktl_ * 64 + swe;                                           \
    ld16(as_ + (row0 + 0 * 128 + (H) * 64 + r8) * (size_t)lda + ko_,                \
         LA + dbo + ((H) * 128 + 0 * 64 + r8) * 64 + ld8);                          \
    ld16(as_ + (row0 + 1 * 128 + (H) * 64 + r8) * (size_t)lda + ko_,                \
         LA + dbo + ((H) * 128 + 1 * 64 + r8) * 64 + ld8); }

#define STAGE_B(H) { size_t ko_ = (size_t)kt1 * 64 + swe;                           \
    ld16(WT + ((size_t)col0 + ((r8 >> 5)) * 64 + (H) * 32 + (r8 & 31)) * (size_t)ldb + ko_,\
         LB + dbo + ((H) * 128 + 0 * 64 + r8) * 64 + ld8);                          \
    ld16(WT + ((size_t)col0 + (2 + (r8 >> 5)) * 64 + (H) * 32 + (r8 & 31)) * (size_t)ldb + ko_,\
         LB + dbo + ((H) * 128 + 1 * 64 + r8) * 64 + ld8); }

#define RD_A(QM) {                                                                  \
    _Pragma("unroll") for (int f = 0; f < 4; ++f)                                   \
      _Pragma("unroll") for (int kk = 0; kk < 2; ++kk)                              \
        af[f][kk] = *(const bf16x8*)(bA + (QM) * 16384 + (wm * 64 + f * 16 + lr) * 128 \
                                     + ((kk * 64 + lg * 16) ^ rxor)); }

#define RD_B(DST, QN) {                                                             \
    _Pragma("unroll") for (int n = 0; n < 2; ++n)                                   \
      _Pragma("unroll") for (int kk = 0; kk < 2; ++kk)                              \
        DST[n][kk] = *(const bf16x8*)(bB + (QN) * 16384 + (wn * 32 + n * 16 + lr) * 128 \
                                     + ((kk * 64 + lg * 16) ^ rxor)); }

#define SYNC_MM(QM, QN, BW) {                                                       \
    __builtin_amdgcn_s_barrier();                                                   \
    __builtin_amdgcn_s_setprio(1);                                                  \
    _Pragma("unroll") for (int kk = 0; kk < 2; ++kk)                                \
      _Pragma("unroll") for (int f = 0; f < 4; ++f)                                 \
        _Pragma("unroll") for (int n = 0; n < 2; ++n)                               \
          acc[(QM) * 4 + f][(QN) * 2 + n] = __builtin_amdgcn_mfma_f32_16x16x32_bf16(\
              BW[n][kk], af[f][kk], acc[(QM) * 4 + f][(QN) * 2 + n], 0, 0, 0);      \
    __builtin_amdgcn_s_setprio(0); }

__global__ __launch_bounds__(512, 2)
void k_gemm256(const u16* __restrict__ A0, const u16* __restrict__ A1,
               const u16* __restrict__ WT, u16* __restrict__ C,
               float* __restrict__ ssum, float* __restrict__ ssq,
               int nkt, int kskt, int lda, int ldb) {
    __shared__ u16 LA[2 * 256 * 64];
    __shared__ u16 LB[2 * 256 * 64];
    const int tid = threadIdx.x;
    const int lane = tid & 63;
    const int wave = tid >> 6;
    const int wm = wave >> 2, wn = wave & 3;   // 2 x 4 waves -> 128x64 C each
    const int lr = lane & 15, lg = lane >> 4;
    const int rxor = (lr & 7) << 4;

    // row-slab XCD mapping (bijective: 632 = 79 rows x 8 cols)
    const int g = (blockIdx.x & 7) * 79 + (blockIdx.x >> 3);
    const size_t row0 = (size_t)(g >> 3) * 256;
    const int col0 = (g & 7) * 256;

    const int r8 = tid >> 3;                      // 0..63 slot-in-issue
    const int ld8 = (tid & 7) * 8;                // dest u16 offset in row
    const int swe = ((ld8 * 2) ^ ((r8 & 7) << 4)) >> 1;  // inv-swizzled src elem

    f32x4 acc[8][4];
#pragma unroll
    for (int i = 0; i < 8; i++)
#pragma unroll
        for (int j = 0; j < 4; j++) acc[i][j] = f32x4{0.f, 0.f, 0.f, 0.f};

    // prologue: tile 0 -> buf 0 (order A0, B0, B1, A1)
    {
        const int kt1 = 0; const int dbo = 0;
        STAGE_A(0) STAGE_B(0) STAGE_B(1) STAGE_A(1)
    }
    VM0;
    __builtin_amdgcn_s_barrier();

    bf16x8 af[4][2], bw[2][2], bw2[2][2];

    for (int t = 0; t < nkt - 1; ++t) {
        const char* bA = (const char*)LA + (t & 1) * 32768;
        const char* bB = (const char*)LB + (t & 1) * 32768;
        const int kt1 = t + 1;
        const int dbo = ((t + 1) & 1) * 16384;
        // p0: read A0+B0, stage A0(next)
        RD_A(0) RD_B(bw, 0) STAGE_A(0) VM4; SYNC_MM(0, 0, bw)
        // p1: read B1 (keep A0), stage B0
        RD_B(bw2, 1) STAGE_B(0) VM4; SYNC_MM(0, 1, bw2)
        // p2: read A1 (keep B1), stage B1 — no vmcnt needed
        RD_A(1) STAGE_B(1) SYNC_MM(1, 1, bw2)
        // p3: read B0 (keep A1), stage A1
        RD_B(bw, 0) STAGE_A(1) VM4; SYNC_MM(1, 0, bw)
    }
    {   // tail tile nkt-1, no staging: waits drain 2 -> 0
        const char* bA = (const char*)LA + ((nkt - 1) & 1) * 32768;
        const char* bB = (const char*)LB + ((nkt - 1) & 1) * 32768;
        RD_A(0) RD_B(bw, 0) VM2; SYNC_MM(0, 0, bw)
        RD_B(bw2, 1) VM0; SYNC_MM(0, 1, bw2)
        RD_A(1) SYNC_MM(1, 1, bw2)
        RD_B(bw, 0) SYNC_MM(1, 0, bw)
    }

    // epilogue: C write (4 consecutive n per lane)
#pragma unroll
    for (int f = 0; f < 8; ++f) {
        size_t m = row0 + wm * 128 + f * 16 + lr;
#pragma unroll
        for (int n = 0; n < 4; ++n) {
            int cb = col0 + wn * 64 + n * 16 + lg * 4;
            u16x4 o;
#pragma unroll
            for (int rg = 0; rg < 4; ++rg) o[rg] = f2bf(acc[f][n][rg]);
            *(u16x4*)&C[m * HID + cb] = o;
        }
    }
    // fused BN column-stats
#pragma unroll
    for (int n = 0; n < 4; ++n) {
#pragma unroll
        for (int rg = 0; rg < 4; ++rg) {
            float s = 0.f, s2 = 0.f;
#pragma unroll
            for (int f = 0; f < 8; ++f) { float v = acc[f][n][rg]; s += v; s2 += v * v; }
#pragma unroll
            for (int mk = 1; mk < 16; mk <<= 1) {
                s += __shfl_xor(s, mk, 64);
                s2 += __shfl_xor(s2, mk, 64);
            }
            if (lr == 0) {
                int cb = col0 + wn * 64 + n * 16 + lg * 4 + rg;
                atomicAdd(&ssum[cb], s);
                atomicAdd(&ssq[cb], s2);
            }
        }
    }
}

// =================== pooling (BN+leaky fused) + MLP ===================
__global__ void k_bounds(const int* __restrict__ gids, int* __restrict__ gstart) {
    int t = threadIdx.x;
    if (t > N_GRAPH) return;
    int lo = 0, hi = N_NODES;
    while (lo < hi) { int mid = (lo + hi) >> 1; if (gids[mid] < t) lo = mid + 1; else hi = mid; }
    gstart[t] = lo;
}

__global__ void k_poolbn(const u16* __restrict__ x,
                         const float* __restrict__ ssum, const float* __restrict__ ssq,
                         const float* __restrict__ gma, const float* __restrict__ bta,
                         const int* __restrict__ gstart, float* __restrict__ hg) {
    int g = blockIdx.x;
    int col = blockIdx.y * 256 + threadIdx.x;
    float m = ssum[col] * (1.0f / N_NODES);
    float var = ssq[col] * (1.0f / N_NODES) - m * m;
    float a = gma[col] * rsqrtf(var + 1e-5f);
    float d = bta[col] - m * a;
    int r0 = gstart[g], r1 = gstart[g + 1];
    float s = 0.f;
    for (int r = r0; r < r1; r++) {
        float f = bf2f(x[(size_t)r * HID + col]) * a + d;
        s += fmaxf(f, 0.01f * f);
    }
    hg[(size_t)g * HID + col] = s / (float)imax(r1 - r0, 1);
}

// k-split partial GEMM: Yp[kc][32][Nc] = X[32][kc-chunk] @ W[chunk][Nc]
__global__ __launch_bounds__(256)
void k_mlp_part(const float* __restrict__ X, const float* __restrict__ W,
                float* __restrict__ Yp, int K, int Nc) {
    __shared__ float xs[32 * 256];
    int t = threadIdx.x;
    int kc = blockIdx.y;
    int n = blockIdx.x * 64 + (t & 63);
    int mg = t >> 6;
#pragma unroll
    for (int l = 0; l < 32; ++l) {
        int e = l * 256 + t;
        xs[e] = X[(size_t)(e >> 8) * K + kc * 256 + (e & 255)];
    }
    __syncthreads();
    float acc[8] = {};
    for (int k = 0; k < 256; ++k) {
        float wv = W[(size_t)(kc * 256 + k) * Nc + n];
#pragma unroll
        for (int i = 0; i < 8; ++i) acc[i] += xs[(mg * 8 + i) * 256 + k] * wv;
    }
#pragma unroll
    for (int i = 0; i < 8; ++i)
        Yp[(size_t)(kc * 32 + mg * 8 + i) * Nc + n] = acc[i];
}

// deterministic reduce over 8 k-chunks + bias + leaky
__global__ void k_mlp_red(const float* __restrict__ Yp, const float* __restrict__ bias,
                          float* __restrict__ Y, int Nc, int leaky) {
    int idx = blockIdx.x * 256 + threadIdx.x;   // m*Nc + n
    int n = idx % Nc;
    float s = 0.f;
#pragma unroll
    for (int kc = 0; kc < 8; ++kc) s += Yp[(size_t)kc * 32 * Nc + idx];
    float v = s + bias[n];
    if (leaky) v = v > 0.f ? v : 0.01f * v;
    Y[idx] = v;
}

__global__ void k_fc3(const float* __restrict__ y2, const float* __restrict__ fw3,
                      const float* __restrict__ fb3, float* __restrict__ out) {
    __shared__ float red[8][32];
    int m = blockIdx.x, t = threadIdx.x;
    int ch = t >> 5, c = t & 31;
    float s = 0.f;
    if (c < NCLS) {
        for (int j = 0; j < 128; ++j) {
            int k = ch * 128 + j;
            s += y2[(size_t)m * PW + k] * fw3[(size_t)k * NCLS + c];
        }
    }
    red[ch][c] = s;
    __syncthreads();
    if (t < NCLS) {
        float a = 0.f;
#pragma unroll
        for (int c2 = 0; c2 < 8; ++c2) a += red[c2][t];
        out[m * NCLS + t] = a + fb3[t];
    }
}

// =================== launcher ===================
extern "C" void kernel_launch(void* const* d_in, const int* in_sizes, int n_in,
                              void* d_out, int out_size, void* d_ws, size_t ws_size,
                              hipStream_t stream) {
    const float* h   = (const float*)d_in[0];
    const int* src   = (const int*)d_in[1];
    const int* dst   = (const int*)d_in[2];
    const int* gids  = (const int*)d_in[3];
    const float* ws1 = (const float*)d_in[4];
    const float* wn1 = (const float*)d_in[5];
    const float* ws2 = (const float*)d_in[7];
    const float* wn2 = (const float*)d_in[8];
    const float* ws3 = (const float*)d_in[10];
    const float* wn3 = (const float*)d_in[11];
    const float* g1  = (const float*)d_in[13];
    const float* be1 = (const float*)d_in[14];
    const float* g2  = (const float*)d_in[15];
    const float* be2 = (const float*)d_in[16];
    const float* g3  = (const float*)d_in[17];
    const float* be3 = (const float*)d_in[18];
    const float* fw1 = (const float*)d_in[19];
    const float* fb1 = (const float*)d_in[20];
    const float* fw2 = (const float*)d_in[21];
    const float* fb2 = (const float*)d_in[22];
    const float* fw3 = (const float*)d_in[23];
    const float* fb3 = (const float*)d_in[24];
    float* out = (float*)d_out;
    (void)in_sizes; (void)n_in; (void)out_size;

    char* base = (char*)d_ws;
    size_t off = 0;
    auto alloc = [&](size_t b) -> char* {
        char* p = base + off;
        off += (b + 255) & ~(size_t)255;
        return p;
    };
    u16* BUF0 = (u16*)alloc((size_t)MPAD2 * HID * 2);
    u16* BUF1 = (u16*)alloc((size_t)MPAD2 * HID * 2);
    u16* BUF2 = (u16*)alloc((size_t)MPAD2 * HID * 2);
    u16* WT   = (u16*)alloc((size_t)HID * 2 * HID * 2);   // reused for layer 2 then 3
    int* cnt    = (int*)alloc(N_NODES * 4);
    int* rowptr = (int*)alloc((N_NODES + 1) * 4);
    int* cursor = (int*)alloc(N_NODES * 4);
    int* csr    = (int*)alloc(N_EDGES * 4);
    float* ssum = (float*)alloc(HID * 4);
    float* ssq  = (float*)alloc(HID * 4);
    int* gstart = (int*)alloc(64 * 4);
    float* hg = (float*)alloc((size_t)N_GRAPH * HID * 4);
    float* y1 = (float*)alloc((size_t)N_GRAPH * HID * 4);
    float* y2 = (float*)alloc((size_t)N_GRAPH * PW * 4);
    // aliases into BUF2 (free at the time of use)
    u16* ACAT = (u16*)((char*)BUF2);                            // layer-1 input [MPAD2][K1]
    u16* W1T  = (u16*)((char*)BUF2 + (size_t)MPAD2 * K1 * 2);   // layer-1 weights [HID][K1]
    float* Yp = (float*)((char*)BUF2);                           // MLP partials (after L3)

    if (off > ws_size) return;   // diagnostic guard

    hipMemsetAsync(cnt, 0, N_NODES * 4, stream);
    hipMemsetAsync(cursor, 0, N_NODES * 4, stream);
    hipMemsetAsync(ACAT, 0, (size_t)MPAD2 * K1 * 2, stream);
    // zero pad rows (20000..20223) of BUF1/BUF2 so gemm A-pads are exact zeros
    hipMemsetAsync(BUF1 + (size_t)N_NODES * HID, 0, (size_t)(MPAD2 - N_NODES) * HID * 2, stream);
    hipMemsetAsync(BUF2 + (size_t)N_NODES * HID, 0, (size_t)(MPAD2 - N_NODES) * HID * 2, stream);

    k_hist<<<(N_EDGES + 255) / 256, 256, 0, stream>>>(dst, cnt);
    k_scan<<<1, 256, 0, stream>>>(cnt, rowptr);
    k_scatter<<<(N_EDGES + 255) / 256, 256, 0, stream>>>(src, dst, rowptr, cursor, csr);

    k_w1t<<<HID, K1, 0, stream>>>(ws1, wn1, W1T);
    k_agg1<<<N_NODES, 192, 0, stream>>>(h, rowptr, csr, ACAT);

    dim3 tb(32, 8);
    // ---- layer 1 (K=192: 3 K-tiles; stats fused into gemm) ----
    hipMemsetAsync(ssum, 0, 2 * HID * 4, stream);
    k_gemm256<<<632, 512, 0, stream>>>(ACAT, ACAT, W1T, BUF0, ssum, ssq, 3, 3, K1, K1);
    // fused BN+leaky+aggregate: BUF0 -> BUF1 (self), BUF2 (neigh mean)
    k_aggbn<<<N_NODES, 256, 0, stream>>>(BUF0, ssum, ssq, g1, be1, rowptr, csr, BUF1, BUF2);
    // ---- layer 2 ----
    k_transpose2<<<dim3(64, 64, 2), tb, 0, stream>>>(ws2, wn2, WT);
    hipMemsetAsync(ssum, 0, 2 * HID * 4, stream);
    k_gemm256<<<632, 512, 0, stream>>>(BUF1, BUF2, WT, BUF0, ssum, ssq, 64, 32, HID, 2 * HID);
    k_aggbn<<<N_NODES, 256, 0, stream>>>(BUF0, ssum, ssq, g2, be2, rowptr, csr, BUF1, BUF2);
    // ---- layer 3 ----
    k_transpose2<<<dim3(64, 64, 2), tb, 0, stream>>>(ws3, wn3, WT);
    hipMemsetAsync(ssum, 0, 2 * HID * 4, stream);
    k_gemm256<<<632, 512, 0, stream>>>(BUF1, BUF2, WT, BUF0, ssum, ssq, 64, 32, HID, 2 * HID);
    // ---- pooling (BN+leaky fused) + MLP head ----
    k_bounds<<<1, 64, 0, stream>>>(gids, gstart);
    k_poolbn<<<dim3(N_GRAPH, HID / 256), 256, 0, stream>>>(BUF0, ssum, ssq, g3, be3, gstart, hg);
    k_mlp_part<<<dim3(HID / 64, 8), 256, 0, stream>>>(hg, fw1, Yp, HID, HID);
    k_mlp_red<<<(N_GRAPH * HID) / 256, 256, 0, stream>>>(Yp, fb1, y1, HID, 1);
    k_mlp_part<<<dim3(PW / 64, 8), 256, 0, stream>>>(y1, fw2, Yp, HID, PW);
    k_mlp_red<<<(N_GRAPH * PW) / 256, 256, 0, stream>>>(Yp, fb2, y2, PW, 1);
    k_fc3<<<N_GRAPH, 256, 0, stream>>>(y2, fw3, fb3, out);
}